// Round 6
// baseline (558.955 us; speedup 1.0000x reference)
//
#include <hip/hip_runtime.h>
#include <math.h>

#define NN 100000
#define EE 800000
#define IN_DIM 128
#define HID 32
#define HEADS 4
#define QKV 128         // HEADS*HID
#define COLS 416        // 3*QKV + HID (q|k|v|skip)
#define QS_W 160        // q(128) + skip(32), fp32
#define KV_W 256        // k(128) + v(128), bf16
#define OUT_DIM 16
#define NB 98           // ceil(NN/1024) scan blocks
#define NTILE 26        // 416/16 col-tiles

typedef __attribute__((ext_vector_type(8))) short short8;
typedef __attribute__((ext_vector_type(4))) float floatx4;

__device__ __forceinline__ unsigned short f2bf(float f) {
    unsigned int u = __float_as_uint(f);
    unsigned int r = (u + 0x7FFF + ((u >> 16) & 1)) >> 16;   // RNE
    return (unsigned short)r;
}
__device__ __forceinline__ float bf2f(unsigned short h) {
    return __uint_as_float((unsigned int)h << 16);
}

// ---------------- pack weights: Wp[K][416], bp[416] ----------------
__global__ void pack_w(const float* __restrict__ Wq, const float* __restrict__ bq,
                       const float* __restrict__ Wk, const float* __restrict__ bk,
                       const float* __restrict__ Wv, const float* __restrict__ bv,
                       const float* __restrict__ Ws, const float* __restrict__ bs,
                       float* __restrict__ Wp, float* __restrict__ bp, int K) {
    int idx = blockIdx.x * blockDim.x + threadIdx.x;
    int total = K * COLS;
    if (idx < total) {
        int k = idx / COLS;
        int j = idx - k * COLS;
        float v;
        if (j < 128)      v = Wq[k * 128 + j];
        else if (j < 256) v = Wk[k * 128 + (j - 128)];
        else if (j < 384) v = Wv[k * 128 + (j - 256)];
        else              v = Ws[k * 32 + (j - 384)];
        Wp[idx] = v;
    }
    if (idx < COLS) {
        float b;
        if (idx < 128)      b = bq[idx];
        else if (idx < 256) b = bk[idx - 128];
        else if (idx < 384) b = bv[idx - 256];
        else                b = bs[idx - 384];
        bp[idx] = b;
    }
}

// ---------------- fragment-pack W (split hi/lo) for MFMA B-operand ------
// Wf[((c*26 + t)*64 + lane)*8 + j] = Wp[(c*32 + (lane>>4)*8 + j)*416 + t*16 + (lane&15)]
__global__ void pack_frag(const float* __restrict__ Wp,
                          unsigned short* __restrict__ Wfh,
                          unsigned short* __restrict__ Wfl, int K) {
    int idx = blockIdx.x * blockDim.x + threadIdx.x;
    int nch = K >> 5;
    if (idx >= nch * NTILE * 64) return;
    int lane = idx & 63;
    int tt = (idx >> 6) % NTILE;
    int c = idx / (NTILE * 64);
    int k0 = c * 32 + (lane >> 4) * 8;
    int col = tt * 16 + (lane & 15);
    #pragma unroll
    for (int j = 0; j < 8; ++j) {
        float w = Wp[(size_t)(k0 + j) * COLS + col];
        unsigned short hi = f2bf(w);
        float rem = w - bf2f(hi);
        Wfh[(size_t)idx * 8 + j] = hi;
        Wfl[(size_t)idx * 8 + j] = f2bf(rem);
    }
}

// ---------------- fp32 -> split bf16 (hi + lo residual) ----------------
__global__ void to_bf16_split(const float* __restrict__ X,
                              unsigned short* __restrict__ Xh,
                              unsigned short* __restrict__ Xl, int total4) {
    int i = blockIdx.x * blockDim.x + threadIdx.x;
    if (i >= total4) return;
    int i4 = i * 4;
    float4 v = *(const float4*)(X + i4);
    ushort4 h = {f2bf(v.x), f2bf(v.y), f2bf(v.z), f2bf(v.w)};
    ushort4 l = {f2bf(v.x - bf2f(h.x)), f2bf(v.y - bf2f(h.y)),
                 f2bf(v.z - bf2f(h.z)), f2bf(v.w - bf2f(h.w))};
    *(ushort4*)(Xh + i4) = h;
    *(ushort4*)(Xl + i4) = l;
}

// ---------------- CSR build ----------------
__global__ void zero_deg(int* __restrict__ deg) {
    int i = blockIdx.x * blockDim.x + threadIdx.x;
    if (i < NN) deg[i] = 0;
}

__global__ void hist_dst(const int* __restrict__ ei, int* __restrict__ deg) {
    int e = blockIdx.x * blockDim.x + threadIdx.x;
    if (e < EE) atomicAdd(&deg[ei[EE + e]], 1);
}

__global__ void block_sum(const int* __restrict__ deg, int* __restrict__ partial) {
    __shared__ int sdata[256];
    int b = blockIdx.x, t = threadIdx.x;
    int sum = 0;
    for (int i = t; i < 1024; i += 256) {
        int g = b * 1024 + i;
        if (g < NN) sum += deg[g];
    }
    sdata[t] = sum; __syncthreads();
    for (int s = 128; s > 0; s >>= 1) {
        if (t < s) sdata[t] += sdata[t + s];
        __syncthreads();
    }
    if (t == 0) partial[b] = sdata[0];
}

// wave-parallel exclusive scan of the NB partials (NB <= 128)
__global__ void scan_partial(int* __restrict__ partial) {
    int l = threadIdx.x;   // 64 threads
    int a = (l < NB) ? partial[l] : 0;
    int b = (l + 64 < NB) ? partial[l + 64] : 0;
    for (int off = 1; off < 64; off <<= 1) {
        int v = __shfl_up(a, off);
        if (l >= off) a += v;
    }
    int tot = __shfl(a, 63);
    for (int off = 1; off < 64; off <<= 1) {
        int v = __shfl_up(b, off);
        if (l >= off) b += v;
    }
    b += tot;
    int ea = __shfl_up(a, 1); if (l == 0) ea = 0;
    int eb = __shfl_up(b, 1); if (l == 0) eb = tot;
    if (l < NB) partial[l] = ea;
    if (l + 64 < NB) partial[l + 64] = eb;
}

__global__ void block_scan(const int* __restrict__ deg, const int* __restrict__ partial,
                           int* __restrict__ roff, int* __restrict__ woff) {
    __shared__ int ssum[256];
    int b = blockIdx.x, t = threadIdx.x;
    int base = b * 1024 + t * 4;
    int v[4]; int s = 0;
    #pragma unroll
    for (int i = 0; i < 4; ++i) {
        int g = base + i;
        v[i] = (g < NN) ? deg[g] : 0;
        s += v[i];
    }
    ssum[t] = s; __syncthreads();
    for (int off = 1; off < 256; off <<= 1) {
        int val = (t >= off) ? ssum[t - off] : 0;
        __syncthreads();
        ssum[t] += val;
        __syncthreads();
    }
    int excl = (t == 0) ? 0 : ssum[t - 1];
    excl += partial[b];
    #pragma unroll
    for (int i = 0; i < 4; ++i) {
        int g = base + i;
        if (g < NN) { roff[g] = excl; woff[g] = excl; }
        excl += v[i];
    }
    if (b == NB - 1 && t == 255) roff[NN] = EE;
}

__global__ void scatter_edges(const int* __restrict__ ei, int* __restrict__ woff,
                              int* __restrict__ esrc) {
    int e = blockIdx.x * blockDim.x + threadIdx.x;
    if (e < EE) {
        int dst = ei[EE + e];
        int pos = atomicAdd(&woff[dst], 1);
        esrc[pos] = ei[e];
    }
}

// ---------------- split-precision MFMA GEMM ----------------
// [N][K] (hi+lo bf16) @ Wf (hi+lo) -> qs fp32 / kvb bf16.
// acc += aH*bH + aH*bL + aL*bH  (lo*lo dropped: ~2^-17 relative).
// Wave computes 32 rows x 64 cols via 2x4 tiles of 16x16x32 MFMA; no LDS.
// XCD swizzle keeps all 7 col-blocks of a row-block on one XCD.
__global__ __launch_bounds__(256) void gemm_mfma(
        const unsigned short* __restrict__ Xh, const unsigned short* __restrict__ Xl,
        const unsigned short* __restrict__ Wfh, const unsigned short* __restrict__ Wfl,
        const float* __restrict__ bp, float* __restrict__ qs,
        unsigned short* __restrict__ kvb, int K) {
    const int tid = threadIdx.x;
    const int lane = tid & 63;
    const int wv = tid >> 6;
    const int RB = (NN + 127) >> 7;
    int b = blockIdx.x;
    int r = (b & 7) + ((b / 56) << 3);
    int cblk = (b >> 3) % 7;
    if (r >= RB) return;
    const int m0 = (r << 7) + (wv << 5);      // this wave's 32-row base
    const int t0 = cblk << 2;                 // first col-tile (of 26)
    const int ntiles = (NTILE - t0 < 4) ? (NTILE - t0) : 4;
    const int ml = lane & 15;
    const int quad = lane >> 4;
    const int nch = K >> 5;

    floatx4 acc[2][4] = {};

    int row0 = m0 + ml;       int r0c = row0 < NN ? row0 : NN - 1;
    int row1 = m0 + 16 + ml;  int r1c = row1 < NN ? row1 : NN - 1;
    const unsigned short* a0ph = Xh + (size_t)r0c * K + quad * 8;
    const unsigned short* a0pl = Xl + (size_t)r0c * K + quad * 8;
    const unsigned short* a1ph = Xh + (size_t)r1c * K + quad * 8;
    const unsigned short* a1pl = Xl + (size_t)r1c * K + quad * 8;

    for (int c = 0; c < nch; ++c) {
        short8 a0h = *(const short8*)(a0ph + c * 32);
        short8 a0l = *(const short8*)(a0pl + c * 32);
        short8 a1h = *(const short8*)(a1ph + c * 32);
        short8 a1l = *(const short8*)(a1pl + c * 32);
        const size_t boff = (((size_t)c * NTILE + t0) * 64 + lane) * 8;
        #pragma unroll
        for (int t = 0; t < 4; ++t) {
            if (t < ntiles) {
                short8 bh = *(const short8*)(Wfh + boff + (size_t)t * 512);
                short8 bl = *(const short8*)(Wfl + boff + (size_t)t * 512);
                acc[0][t] = __builtin_amdgcn_mfma_f32_16x16x32_bf16(a0h, bh, acc[0][t], 0, 0, 0);
                acc[0][t] = __builtin_amdgcn_mfma_f32_16x16x32_bf16(a0h, bl, acc[0][t], 0, 0, 0);
                acc[0][t] = __builtin_amdgcn_mfma_f32_16x16x32_bf16(a0l, bh, acc[0][t], 0, 0, 0);
                acc[1][t] = __builtin_amdgcn_mfma_f32_16x16x32_bf16(a1h, bh, acc[1][t], 0, 0, 0);
                acc[1][t] = __builtin_amdgcn_mfma_f32_16x16x32_bf16(a1h, bl, acc[1][t], 0, 0, 0);
                acc[1][t] = __builtin_amdgcn_mfma_f32_16x16x32_bf16(a1l, bh, acc[1][t], 0, 0, 0);
            }
        }
    }

    #pragma unroll
    for (int t = 0; t < 4; ++t) {
        if (t >= ntiles) break;
        int tg = t0 + t;
        int col = (tg << 4) + ml;
        float bias = bp[col];
        #pragma unroll
        for (int mt = 0; mt < 2; ++mt) {
            int rbase = m0 + mt * 16 + quad * 4;
            #pragma unroll
            for (int rr = 0; rr < 4; ++rr) {
                int row = rbase + rr;
                if (row >= NN) continue;
                float val = acc[mt][t][rr] + bias;
                if (tg < 8)
                    qs[(size_t)row * QS_W + col] = val;
                else if (tg < 16)
                    kvb[(size_t)row * KV_W + (col - 128)] = f2bf(val);
                else if (tg < 24)
                    kvb[(size_t)row * KV_W + 128 + (col - 256)] = f2bf(val);
                else
                    qs[(size_t)row * QS_W + 128 + (col - 384)] = val;
            }
        }
    }
}

// ---------------- fused attention: one wave per dst node ----------------
// Dual-chain online softmax + 8-deep gather batching.
// lanes 0..31: q fragment; lanes 32..63: v accumulator.
#define ATTN_STEP(kv, M, S, ACC) {                                           \
    float part = q4.x * (kv).x + q4.y * (kv).y + q4.z * (kv).z + q4.w * (kv).w; \
    part += __shfl_xor(part, 1);                                             \
    part += __shfl_xor(part, 2);                                             \
    part += __shfl_xor(part, 4);                                             \
    float a = __shfl(part, hsrc) * 0.17677669529663687f;                     \
    float mn = fmaxf(M, a);                                                  \
    float corr = __expf(M - mn);                                             \
    float p = __expf(a - mn);                                                \
    S = S * corr + p;                                                        \
    (ACC).x = (ACC).x * corr + p * (kv).x;                                   \
    (ACC).y = (ACC).y * corr + p * (kv).y;                                   \
    (ACC).z = (ACC).z * corr + p * (kv).z;                                   \
    (ACC).w = (ACC).w * corr + p * (kv).w;                                   \
    M = mn; }

__device__ __forceinline__ float4 ld_kv(const unsigned short* __restrict__ kvb,
                                        int src, int lane) {
    ushort4 t = *(const ushort4*)(kvb + (size_t)src * KV_W + 4 * lane);
    return make_float4(bf2f(t.x), bf2f(t.y), bf2f(t.z), bf2f(t.w));
}

__global__ __launch_bounds__(256) void fused_attn(
        const float* __restrict__ qs, const unsigned short* __restrict__ kvb,
        const int* __restrict__ roff, const int* __restrict__ esrc,
        float* __restrict__ hout,
        unsigned short* __restrict__ hh, unsigned short* __restrict__ hl) {
    const int lane = threadIdx.x & 63;
    const int w = (blockIdx.x * blockDim.x + threadIdx.x) >> 6;
    if (w >= NN) return;
    const int n = w;
    const int kl = lane & 31;
    const int hsrc = kl & 24;
    const float* row = qs + (size_t)n * QS_W;
    const float* qaddr = (lane < 32) ? (row + 4 * kl) : (row + 128 + 4 * (kl & 7));
    float4 q4 = *(const float4*)qaddr;

    float mA = -INFINITY, sA = 0.f, mB = -INFINITY, sB = 0.f;
    float4 accA = make_float4(0.f, 0.f, 0.f, 0.f);
    float4 accB = make_float4(0.f, 0.f, 0.f, 0.f);
    const int e0 = roff[n], e1 = roff[n + 1];
    int e = e0;
    for (; e + 8 <= e1; e += 8) {
        int s0 = esrc[e],     s1 = esrc[e + 1], s2 = esrc[e + 2], s3 = esrc[e + 3];
        int s4 = esrc[e + 4], s5 = esrc[e + 5], s6 = esrc[e + 6], s7 = esrc[e + 7];
        float4 kv0 = ld_kv(kvb, s0, lane);
        float4 kv1 = ld_kv(kvb, s1, lane);
        float4 kv2 = ld_kv(kvb, s2, lane);
        float4 kv3 = ld_kv(kvb, s3, lane);
        float4 kv4 = ld_kv(kvb, s4, lane);
        float4 kv5 = ld_kv(kvb, s5, lane);
        float4 kv6 = ld_kv(kvb, s6, lane);
        float4 kv7 = ld_kv(kvb, s7, lane);
        ATTN_STEP(kv0, mA, sA, accA); ATTN_STEP(kv1, mB, sB, accB);
        ATTN_STEP(kv2, mA, sA, accA); ATTN_STEP(kv3, mB, sB, accB);
        ATTN_STEP(kv4, mA, sA, accA); ATTN_STEP(kv5, mB, sB, accB);
        ATTN_STEP(kv6, mA, sA, accA); ATTN_STEP(kv7, mB, sB, accB);
    }
    for (; e + 4 <= e1; e += 4) {
        int s0 = esrc[e], s1 = esrc[e + 1], s2 = esrc[e + 2], s3 = esrc[e + 3];
        float4 kv0 = ld_kv(kvb, s0, lane);
        float4 kv1 = ld_kv(kvb, s1, lane);
        float4 kv2 = ld_kv(kvb, s2, lane);
        float4 kv3 = ld_kv(kvb, s3, lane);
        ATTN_STEP(kv0, mA, sA, accA); ATTN_STEP(kv1, mB, sB, accB);
        ATTN_STEP(kv2, mA, sA, accA); ATTN_STEP(kv3, mB, sB, accB);
    }
    for (; e < e1; ++e) {
        float4 kv = ld_kv(kvb, esrc[e], lane);
        ATTN_STEP(kv, mA, sA, accA);
    }
    // merge chains (guard -inf - -inf = NaN for empty/odd chains)
    float mM = fmaxf(mA, mB);
    float cA = (mA == -INFINITY) ? 0.f : __expf(mA - mM);
    float cB = (mB == -INFINITY) ? 0.f : __expf(mB - mM);
    float s = sA * cA + sB * cB;
    float4 acc;
    acc.x = accA.x * cA + accB.x * cB;
    acc.y = accA.y * cA + accB.y * cB;
    acc.z = accA.z * cA + accB.z * cB;
    acc.w = accA.w * cA + accB.w * cB;

    float inv = (s > 0.f) ? 1.f / s : 0.f;
    float4 o;
    o.x = acc.x * inv; o.y = acc.y * inv; o.z = acc.z * inv; o.w = acc.w * inv;
    o.x += __shfl_xor(o.x, 8);  o.y += __shfl_xor(o.y, 8);  o.z += __shfl_xor(o.z, 8);  o.w += __shfl_xor(o.w, 8);
    o.x += __shfl_xor(o.x, 16); o.y += __shfl_xor(o.y, 16); o.z += __shfl_xor(o.z, 16); o.w += __shfl_xor(o.w, 16);
    if (lane >= 32 && lane < 40) {
        float4 rr;
        rr.x = fmaxf(o.x * 0.25f + q4.x, 0.f);   // q4 holds skip in these lanes
        rr.y = fmaxf(o.y * 0.25f + q4.y, 0.f);
        rr.z = fmaxf(o.z * 0.25f + q4.z, 0.f);
        rr.w = fmaxf(o.w * 0.25f + q4.w, 0.f);
        int c0 = 4 * (lane - 32);
        *(float4*)(hout + (size_t)n * HID + c0) = rr;
        ushort4 uh = {f2bf(rr.x), f2bf(rr.y), f2bf(rr.z), f2bf(rr.w)};
        ushort4 ul = {f2bf(rr.x - bf2f(uh.x)), f2bf(rr.y - bf2f(uh.y)),
                      f2bf(rr.z - bf2f(uh.z)), f2bf(rr.w - bf2f(uh.w))};
        *(ushort4*)(hh + (size_t)n * HID + c0) = uh;
        *(ushort4*)(hl + (size_t)n * HID + c0) = ul;
    }
}

// ---------------- final linear: out = h @ Wout + bout --------------------
__global__ void out_linear(const float* __restrict__ h, const float* __restrict__ Wout,
                           const float* __restrict__ bout, float* __restrict__ out) {
    int idx = blockIdx.x * blockDim.x + threadIdx.x;
    if (idx >= NN * OUT_DIM) return;
    int n = idx >> 4;
    int j = idx & 15;
    float accv = bout[j];
    #pragma unroll
    for (int k = 0; k < HID; ++k)
        accv += h[(size_t)n * HID + k] * Wout[k * OUT_DIM + j];
    out[idx] = accv;
}

extern "C" void kernel_launch(void* const* d_in, const int* in_sizes, int n_in,
                              void* d_out, int out_size, void* d_ws, size_t ws_size,
                              hipStream_t stream) {
    const float* x  = (const float*)d_in[0];
    const int*   ei = (const int*)d_in[1];
    const float* l0w[8]; const float* l1w[8];
    for (int i = 0; i < 8; ++i) { l0w[i] = (const float*)d_in[2 + i]; l1w[i] = (const float*)d_in[10 + i]; }
    const float* Wout = (const float*)d_in[18];
    const float* bout = (const float*)d_in[19];
    float* out = (float*)d_out;

    // workspace layout
    float* ws = (float*)d_ws;
    float* qs   = ws;                           // NN*160 floats
    float* h0   = qs + (size_t)NN * QS_W;       // NN*32
    float* Wp0  = h0 + (size_t)NN * HID;        // 128*416
    float* bp0  = Wp0 + 128 * COLS;             // 416
    float* Wp1  = bp0 + COLS;                   // 32*416
    float* bp1  = Wp1 + 32 * COLS;              // 416
    unsigned short* kvb  = (unsigned short*)(bp1 + COLS);    // NN*256 bf16
    unsigned short* xh   = kvb + (size_t)NN * KV_W;          // NN*128
    unsigned short* xl   = xh + (size_t)NN * IN_DIM;         // NN*128
    unsigned short* hh   = xl + (size_t)NN * IN_DIM;         // NN*32
    unsigned short* hl   = hh + (size_t)NN * HID;            // NN*32
    unsigned short* Wf0h = hl + (size_t)NN * HID;            // 4*26*64*8
    unsigned short* Wf0l = Wf0h + 4 * NTILE * 64 * 8;
    unsigned short* Wf1h = Wf0l + 4 * NTILE * 64 * 8;        // 1*26*64*8
    unsigned short* Wf1l = Wf1h + NTILE * 64 * 8;
    int* ibase  = (int*)(Wf1l + NTILE * 64 * 8);
    int* deg     = ibase;                       // NN
    int* roff    = deg + NN;                    // NN+1
    int* woff    = roff + NN + 1;               // NN
    int* partial = woff + NN;                   // NB
    int* esrc    = partial + NB;                // EE

    // pack weights + fragment-pack + split-convert x
    pack_w<<<(128 * COLS + 255) / 256, 256, 0, stream>>>(
        l0w[0], l0w[1], l0w[2], l0w[3], l0w[4], l0w[5], l0w[6], l0w[7], Wp0, bp0, 128);
    pack_w<<<(32 * COLS + 255) / 256, 256, 0, stream>>>(
        l1w[0], l1w[1], l1w[2], l1w[3], l1w[4], l1w[5], l1w[6], l1w[7], Wp1, bp1, 32);
    pack_frag<<<(4 * NTILE * 64 + 255) / 256, 256, 0, stream>>>(Wp0, Wf0h, Wf0l, 128);
    pack_frag<<<(1 * NTILE * 64 + 255) / 256, 256, 0, stream>>>(Wp1, Wf1h, Wf1l, 32);
    to_bf16_split<<<(NN * IN_DIM / 4 + 255) / 256, 256, 0, stream>>>(x, xh, xl, NN * IN_DIM / 4);

    // CSR build (once; reused by both layers)
    zero_deg<<<(NN + 255) / 256, 256, 0, stream>>>(deg);
    hist_dst<<<(EE + 255) / 256, 256, 0, stream>>>(ei, deg);
    block_sum<<<NB, 256, 0, stream>>>(deg, partial);
    scan_partial<<<1, 64, 0, stream>>>(partial);
    block_scan<<<NB, 256, 0, stream>>>(deg, partial, roff, woff);
    scatter_edges<<<(EE + 255) / 256, 256, 0, stream>>>(ei, woff, esrc);

    const int RB = (NN + 127) / 128;             // 782
    const int gemm_blocks = 56 * ((RB + 7) / 8); // swizzle-bijective
    int attn_blocks = (NN * 64 + 255) / 256;     // one wave per node

    // layer 0
    gemm_mfma<<<gemm_blocks, 256, 0, stream>>>(xh, xl, Wf0h, Wf0l, bp0, qs, kvb, 128);
    fused_attn<<<attn_blocks, 256, 0, stream>>>(qs, kvb, roff, esrc, h0, hh, hl);

    // layer 1
    gemm_mfma<<<gemm_blocks, 256, 0, stream>>>(hh, hl, Wf1h, Wf1l, bp1, qs, kvb, 32);
    fused_attn<<<attn_blocks, 256, 0, stream>>>(qs, kvb, roff, esrc, h0, hh, hl);

    // output linear
    out_linear<<<(NN * OUT_DIM + 255) / 256, 256, 0, stream>>>(h0, Wout, bout, out);
}

// Round 7
// 493.795 us; speedup vs baseline: 1.1320x; 1.1320x over previous
//
#include <hip/hip_runtime.h>
#include <math.h>

#define NN 100000
#define EE 800000
#define IN_DIM 128
#define HID 32
#define HEADS 4
#define QKV 128         // HEADS*HID
#define COLS 416        // 3*QKV + HID (q|k|v|skip)
#define QS_W 160        // q(128) + skip(32), fp32
#define KV_W 256        // interleaved bf16: 32 groups of [k x4 | v x4]
#define OUT_DIM 16
#define NB 98           // ceil(NN/1024) scan blocks
#define NTILE 26        // 416/16 col-tiles

typedef __attribute__((ext_vector_type(8))) short short8;
typedef __attribute__((ext_vector_type(4))) float floatx4;

__device__ __forceinline__ unsigned short f2bf(float f) {
    unsigned int u = __float_as_uint(f);
    unsigned int r = (u + 0x7FFF + ((u >> 16) & 1)) >> 16;   // RNE
    return (unsigned short)r;
}
__device__ __forceinline__ float bf2f(unsigned short h) {
    return __uint_as_float((unsigned int)h << 16);
}
__device__ __forceinline__ float bf_lo(unsigned int d) {
    return __uint_as_float(d << 16);
}
__device__ __forceinline__ float bf_hi(unsigned int d) {
    return __uint_as_float(d & 0xFFFF0000u);
}

// ---------------- pack weights: Wp[K][416], bp[416] ----------------
__global__ void pack_w(const float* __restrict__ Wq, const float* __restrict__ bq,
                       const float* __restrict__ Wk, const float* __restrict__ bk,
                       const float* __restrict__ Wv, const float* __restrict__ bv,
                       const float* __restrict__ Ws, const float* __restrict__ bs,
                       float* __restrict__ Wp, float* __restrict__ bp, int K) {
    int idx = blockIdx.x * blockDim.x + threadIdx.x;
    int total = K * COLS;
    if (idx < total) {
        int k = idx / COLS;
        int j = idx - k * COLS;
        float v;
        if (j < 128)      v = Wq[k * 128 + j];
        else if (j < 256) v = Wk[k * 128 + (j - 128)];
        else if (j < 384) v = Wv[k * 128 + (j - 256)];
        else              v = Ws[k * 32 + (j - 384)];
        Wp[idx] = v;
    }
    if (idx < COLS) {
        float b;
        if (idx < 128)      b = bq[idx];
        else if (idx < 256) b = bk[idx - 128];
        else if (idx < 384) b = bv[idx - 256];
        else                b = bs[idx - 384];
        bp[idx] = b;
    }
}

// ---------------- fragment-pack W (split hi/lo) for MFMA operand --------
// Wf[((c*26 + t)*64 + lane)*8 + j] = Wp[(c*32 + (lane>>4)*8 + j)*416 + t*16 + (lane&15)]
// (A- and B-operand register layouts are identical for 16x16x32.)
__global__ void pack_frag(const float* __restrict__ Wp,
                          unsigned short* __restrict__ Wfh,
                          unsigned short* __restrict__ Wfl, int K) {
    int idx = blockIdx.x * blockDim.x + threadIdx.x;
    int nch = K >> 5;
    if (idx >= nch * NTILE * 64) return;
    int lane = idx & 63;
    int tt = (idx >> 6) % NTILE;
    int c = idx / (NTILE * 64);
    int k0 = c * 32 + (lane >> 4) * 8;
    int col = tt * 16 + (lane & 15);
    #pragma unroll
    for (int j = 0; j < 8; ++j) {
        float w = Wp[(size_t)(k0 + j) * COLS + col];
        unsigned short hi = f2bf(w);
        float rem = w - bf2f(hi);
        Wfh[(size_t)idx * 8 + j] = hi;
        Wfl[(size_t)idx * 8 + j] = f2bf(rem);
    }
}

// ---------------- fp32 -> split bf16 (hi + lo residual) ----------------
__global__ void to_bf16_split(const float* __restrict__ X,
                              unsigned short* __restrict__ Xh,
                              unsigned short* __restrict__ Xl, int total4) {
    int i = blockIdx.x * blockDim.x + threadIdx.x;
    if (i >= total4) return;
    int i4 = i * 4;
    float4 v = *(const float4*)(X + i4);
    ushort4 h = {f2bf(v.x), f2bf(v.y), f2bf(v.z), f2bf(v.w)};
    ushort4 l = {f2bf(v.x - bf2f(h.x)), f2bf(v.y - bf2f(h.y)),
                 f2bf(v.z - bf2f(h.z)), f2bf(v.w - bf2f(h.w))};
    *(ushort4*)(Xh + i4) = h;
    *(ushort4*)(Xl + i4) = l;
}

// ---------------- CSR build ----------------
__global__ void zero_deg(int* __restrict__ deg) {
    int i = blockIdx.x * blockDim.x + threadIdx.x;
    if (i < NN) deg[i] = 0;
}

__global__ void hist_dst(const int* __restrict__ ei, int* __restrict__ deg) {
    int e = blockIdx.x * blockDim.x + threadIdx.x;
    if (e < EE) atomicAdd(&deg[ei[EE + e]], 1);
}

__global__ void block_sum(const int* __restrict__ deg, int* __restrict__ partial) {
    __shared__ int sdata[256];
    int b = blockIdx.x, t = threadIdx.x;
    int sum = 0;
    for (int i = t; i < 1024; i += 256) {
        int g = b * 1024 + i;
        if (g < NN) sum += deg[g];
    }
    sdata[t] = sum; __syncthreads();
    for (int s = 128; s > 0; s >>= 1) {
        if (t < s) sdata[t] += sdata[t + s];
        __syncthreads();
    }
    if (t == 0) partial[b] = sdata[0];
}

// wave-parallel exclusive scan of the NB partials (NB <= 128)
__global__ void scan_partial(int* __restrict__ partial) {
    int l = threadIdx.x;   // 64 threads
    int a = (l < NB) ? partial[l] : 0;
    int b = (l + 64 < NB) ? partial[l + 64] : 0;
    for (int off = 1; off < 64; off <<= 1) {
        int v = __shfl_up(a, off);
        if (l >= off) a += v;
    }
    int tot = __shfl(a, 63);
    for (int off = 1; off < 64; off <<= 1) {
        int v = __shfl_up(b, off);
        if (l >= off) b += v;
    }
    b += tot;
    int ea = __shfl_up(a, 1); if (l == 0) ea = 0;
    int eb = __shfl_up(b, 1); if (l == 0) eb = tot;
    if (l < NB) partial[l] = ea;
    if (l + 64 < NB) partial[l + 64] = eb;
}

__global__ void block_scan(const int* __restrict__ deg, const int* __restrict__ partial,
                           int* __restrict__ roff, int* __restrict__ woff) {
    __shared__ int ssum[256];
    int b = blockIdx.x, t = threadIdx.x;
    int base = b * 1024 + t * 4;
    int v[4]; int s = 0;
    #pragma unroll
    for (int i = 0; i < 4; ++i) {
        int g = base + i;
        v[i] = (g < NN) ? deg[g] : 0;
        s += v[i];
    }
    ssum[t] = s; __syncthreads();
    for (int off = 1; off < 256; off <<= 1) {
        int val = (t >= off) ? ssum[t - off] : 0;
        __syncthreads();
        ssum[t] += val;
        __syncthreads();
    }
    int excl = (t == 0) ? 0 : ssum[t - 1];
    excl += partial[b];
    #pragma unroll
    for (int i = 0; i < 4; ++i) {
        int g = base + i;
        if (g < NN) { roff[g] = excl; woff[g] = excl; }
        excl += v[i];
    }
    if (b == NB - 1 && t == 255) roff[NN] = EE;
}

__global__ void scatter_edges(const int* __restrict__ ei, int* __restrict__ woff,
                              int* __restrict__ esrc) {
    int e = blockIdx.x * blockDim.x + threadIdx.x;
    if (e < EE) {
        int dst = ei[EE + e];
        int pos = atomicAdd(&woff[dst], 1);
        esrc[pos] = ei[e];
    }
}

// ---------------- split-precision MFMA GEMM (swapped operands) ----------
// D = W^T * X^T computed as mfma(w_frag, x_frag): each lane ends up holding
// 4 CONSECUTIVE output columns for one node -> float4/ushort4 stores.
// acc += wH*xH + wL*xH + wH*xL (lo*lo dropped, ~2^-17 relative).
// kvb epilogue writes the INTERLEAVED layout: group g = [k4g..k4g+3 | v4g..v4g+3].
__global__ __launch_bounds__(256) void gemm_mfma(
        const unsigned short* __restrict__ Xh, const unsigned short* __restrict__ Xl,
        const unsigned short* __restrict__ Wfh, const unsigned short* __restrict__ Wfl,
        const float* __restrict__ bp, float* __restrict__ qs,
        unsigned short* __restrict__ kvb, int K) {
    const int tid = threadIdx.x;
    const int lane = tid & 63;
    const int wv = tid >> 6;
    const int RB = (NN + 127) >> 7;
    int b = blockIdx.x;
    int r = (b & 7) + ((b / 56) << 3);
    int cblk = (b >> 3) % 7;
    if (r >= RB) return;
    const int m0 = (r << 7) + (wv << 5);      // this wave's 32-row base
    const int t0 = cblk << 2;                 // first col-tile (of 26)
    const int ntiles = (NTILE - t0 < 4) ? (NTILE - t0) : 4;
    const int ml = lane & 15;
    const int quad = lane >> 4;
    const int nch = K >> 5;

    floatx4 acc[2][4] = {};

    int row0 = m0 + ml;       int r0c = row0 < NN ? row0 : NN - 1;
    int row1 = m0 + 16 + ml;  int r1c = row1 < NN ? row1 : NN - 1;
    const unsigned short* a0ph = Xh + (size_t)r0c * K + quad * 8;
    const unsigned short* a0pl = Xl + (size_t)r0c * K + quad * 8;
    const unsigned short* a1ph = Xh + (size_t)r1c * K + quad * 8;
    const unsigned short* a1pl = Xl + (size_t)r1c * K + quad * 8;

    for (int c = 0; c < nch; ++c) {
        short8 x0h = *(const short8*)(a0ph + c * 32);
        short8 x0l = *(const short8*)(a0pl + c * 32);
        short8 x1h = *(const short8*)(a1ph + c * 32);
        short8 x1l = *(const short8*)(a1pl + c * 32);
        const size_t boff = (((size_t)c * NTILE + t0) * 64 + lane) * 8;
        #pragma unroll
        for (int t = 0; t < 4; ++t) {
            if (t < ntiles) {
                short8 wh = *(const short8*)(Wfh + boff + (size_t)t * 512);
                short8 wl = *(const short8*)(Wfl + boff + (size_t)t * 512);
                acc[0][t] = __builtin_amdgcn_mfma_f32_16x16x32_bf16(wh, x0h, acc[0][t], 0, 0, 0);
                acc[0][t] = __builtin_amdgcn_mfma_f32_16x16x32_bf16(wl, x0h, acc[0][t], 0, 0, 0);
                acc[0][t] = __builtin_amdgcn_mfma_f32_16x16x32_bf16(wh, x0l, acc[0][t], 0, 0, 0);
                acc[1][t] = __builtin_amdgcn_mfma_f32_16x16x32_bf16(wh, x1h, acc[1][t], 0, 0, 0);
                acc[1][t] = __builtin_amdgcn_mfma_f32_16x16x32_bf16(wl, x1h, acc[1][t], 0, 0, 0);
                acc[1][t] = __builtin_amdgcn_mfma_f32_16x16x32_bf16(wh, x1l, acc[1][t], 0, 0, 0);
            }
        }
    }

    // epilogue: lane holds cols [tg*16+quad*4 .. +3] for node m0+mt*16+ml
    #pragma unroll
    for (int t = 0; t < 4; ++t) {
        if (t >= ntiles) break;
        int tg = t0 + t;
        int c0 = (tg << 4) + (quad << 2);
        float4 b4 = *(const float4*)(bp + c0);
        #pragma unroll
        for (int mt = 0; mt < 2; ++mt) {
            int node = m0 + mt * 16 + ml;
            if (node >= NN) continue;
            float v0 = acc[mt][t][0] + b4.x;
            float v1 = acc[mt][t][1] + b4.y;
            float v2 = acc[mt][t][2] + b4.z;
            float v3 = acc[mt][t][3] + b4.w;
            if (tg < 8) {                      // q -> fp32
                *(float4*)(qs + (size_t)node * QS_W + c0) = make_float4(v0, v1, v2, v3);
            } else if (tg < 16) {              // k -> bf16 interleaved (group +0)
                int cc = c0 - 128;
                ushort4 u = {f2bf(v0), f2bf(v1), f2bf(v2), f2bf(v3)};
                *(ushort4*)(kvb + (size_t)node * KV_W + (cc << 1)) = u;
            } else if (tg < 24) {              // v -> bf16 interleaved (group +4)
                int cc = c0 - 256;
                ushort4 u = {f2bf(v0), f2bf(v1), f2bf(v2), f2bf(v3)};
                *(ushort4*)(kvb + (size_t)node * KV_W + (cc << 1) + 4) = u;
            } else {                           // skip -> fp32
                *(float4*)(qs + (size_t)node * QS_W + 128 + (c0 - 384)) = make_float4(v0, v1, v2, v3);
            }
        }
    }
}

// ---------------- fused attention: half-wave per edge ----------------
// Lane kl (=lane&31) owns channels 4kl..4kl+3 of BOTH k and v (interleaved
// kvb). Half-wave A (lanes 0..31) takes even edges, B odd edges — the two
// online-softmax chains run in parallel lanes, merged via xor-32 at the end.
// Head h = kl>>3; xor{1,2,4} butterfly gives all 8 lanes the head dot.
#define ATTN_STEP(u, valid) {                                                \
    float k0 = bf_lo((u).x), k1 = bf_hi((u).x);                              \
    float k2 = bf_lo((u).y), k3 = bf_hi((u).y);                              \
    float v0 = bf_lo((u).z), v1 = bf_hi((u).z);                              \
    float v2 = bf_lo((u).w), v3 = bf_hi((u).w);                              \
    float part = q4.x * k0 + q4.y * k1 + q4.z * k2 + q4.w * k3;              \
    part += __shfl_xor(part, 1);                                             \
    part += __shfl_xor(part, 2);                                             \
    part += __shfl_xor(part, 4);                                             \
    float a = (valid) ? part * 0.17677669529663687f : -INFINITY;             \
    float mn = fmaxf(m, a);                                                  \
    float corr = __expf(m - mn);                                             \
    float p = __expf(a - mn);                                                \
    s = s * corr + p;                                                        \
    acc.x = acc.x * corr + p * v0;                                           \
    acc.y = acc.y * corr + p * v1;                                           \
    acc.z = acc.z * corr + p * v2;                                           \
    acc.w = acc.w * corr + p * v3;                                           \
    m = mn; }

__global__ __launch_bounds__(256) void fused_attn(
        const float* __restrict__ qs, const unsigned short* __restrict__ kvb,
        const int* __restrict__ roff, const int* __restrict__ esrc,
        float* __restrict__ hout,
        unsigned short* __restrict__ hh, unsigned short* __restrict__ hl) {
    const int lane = threadIdx.x & 63;
    const int w = (blockIdx.x * blockDim.x + threadIdx.x) >> 6;
    if (w >= NN) return;
    const int n = w;
    const int kl = lane & 31;
    const int hw = lane >> 5;          // 0: even edges, 1: odd edges
    float4 q4 = *(const float4*)(qs + (size_t)n * QS_W + 4 * kl);

    float m = -INFINITY, s = 0.f;
    float4 acc = make_float4(0.f, 0.f, 0.f, 0.f);
    const int e0 = roff[n];
    const int cnt = roff[n + 1] - e0;
    const int half_steps = cnt >> 1;
    int i = 0;
    for (; i + 4 <= half_steps; i += 4) {
        int b0 = esrc[e0 + 2 * i + hw];
        int b1 = esrc[e0 + 2 * i + 2 + hw];
        int b2 = esrc[e0 + 2 * i + 4 + hw];
        int b3 = esrc[e0 + 2 * i + 6 + hw];
        uint4 u0 = *(const uint4*)(kvb + (size_t)b0 * KV_W + 8 * kl);
        uint4 u1 = *(const uint4*)(kvb + (size_t)b1 * KV_W + 8 * kl);
        uint4 u2 = *(const uint4*)(kvb + (size_t)b2 * KV_W + 8 * kl);
        uint4 u3 = *(const uint4*)(kvb + (size_t)b3 * KV_W + 8 * kl);
        ATTN_STEP(u0, true); ATTN_STEP(u1, true);
        ATTN_STEP(u2, true); ATTN_STEP(u3, true);
    }
    for (; i < half_steps; ++i) {
        int b0 = esrc[e0 + 2 * i + hw];
        uint4 u0 = *(const uint4*)(kvb + (size_t)b0 * KV_W + 8 * kl);
        ATTN_STEP(u0, true);
    }
    if (cnt & 1) {   // last (even-index) edge: half A only
        int b0 = esrc[e0 + cnt - 1];
        uint4 u0 = *(const uint4*)(kvb + (size_t)b0 * KV_W + 8 * kl);
        ATTN_STEP(u0, hw == 0);
    }

    // merge half-waves (guard empty chains: m == -inf may carry NaN s/acc)
    float mo = __shfl_xor(m, 32);
    float so = __shfl_xor(s, 32);
    float4 ao;
    ao.x = __shfl_xor(acc.x, 32);
    ao.y = __shfl_xor(acc.y, 32);
    ao.z = __shfl_xor(acc.z, 32);
    ao.w = __shfl_xor(acc.w, 32);
    bool selfE = (m == -INFINITY), otherE = (mo == -INFINITY);
    float mM = fmaxf(m, mo);
    float cS = selfE ? 0.f : __expf(m - mM);
    float cO = otherE ? 0.f : __expf(mo - mM);
    float sT = (selfE ? 0.f : s) * cS + (otherE ? 0.f : so) * cO;
    float4 aT;
    aT.x = (selfE ? 0.f : acc.x) * cS + (otherE ? 0.f : ao.x) * cO;
    aT.y = (selfE ? 0.f : acc.y) * cS + (otherE ? 0.f : ao.y) * cO;
    aT.z = (selfE ? 0.f : acc.z) * cS + (otherE ? 0.f : ao.z) * cO;
    aT.w = (selfE ? 0.f : acc.w) * cS + (otherE ? 0.f : ao.w) * cO;

    float inv = (sT > 0.f) ? 1.f / sT : 0.f;
    float4 o;
    o.x = aT.x * inv; o.y = aT.y * inv; o.z = aT.z * inv; o.w = aT.w * inv;
    // sum over heads: lanes with same kl&7 across the 4 head groups
    o.x += __shfl_xor(o.x, 8);  o.y += __shfl_xor(o.y, 8);  o.z += __shfl_xor(o.z, 8);  o.w += __shfl_xor(o.w, 8);
    o.x += __shfl_xor(o.x, 16); o.y += __shfl_xor(o.y, 16); o.z += __shfl_xor(o.z, 16); o.w += __shfl_xor(o.w, 16);
    if (lane < 8) {
        float4 sk = *(const float4*)(qs + (size_t)n * QS_W + 128 + 4 * lane);
        float4 rr;
        rr.x = fmaxf(o.x * 0.25f + sk.x, 0.f);
        rr.y = fmaxf(o.y * 0.25f + sk.y, 0.f);
        rr.z = fmaxf(o.z * 0.25f + sk.z, 0.f);
        rr.w = fmaxf(o.w * 0.25f + sk.w, 0.f);
        int c0 = 4 * lane;
        *(float4*)(hout + (size_t)n * HID + c0) = rr;
        ushort4 uh = {f2bf(rr.x), f2bf(rr.y), f2bf(rr.z), f2bf(rr.w)};
        ushort4 ul = {f2bf(rr.x - bf2f(uh.x)), f2bf(rr.y - bf2f(uh.y)),
                      f2bf(rr.z - bf2f(uh.z)), f2bf(rr.w - bf2f(uh.w))};
        *(ushort4*)(hh + (size_t)n * HID + c0) = uh;
        *(ushort4*)(hl + (size_t)n * HID + c0) = ul;
    }
}

// ---------------- final linear: out = h @ Wout + bout --------------------
__global__ void out_linear(const float* __restrict__ h, const float* __restrict__ Wout,
                           const float* __restrict__ bout, float* __restrict__ out) {
    int idx = blockIdx.x * blockDim.x + threadIdx.x;
    if (idx >= NN * OUT_DIM) return;
    int n = idx >> 4;
    int j = idx & 15;
    float accv = bout[j];
    #pragma unroll
    for (int k = 0; k < HID; ++k)
        accv += h[(size_t)n * HID + k] * Wout[k * OUT_DIM + j];
    out[idx] = accv;
}

extern "C" void kernel_launch(void* const* d_in, const int* in_sizes, int n_in,
                              void* d_out, int out_size, void* d_ws, size_t ws_size,
                              hipStream_t stream) {
    const float* x  = (const float*)d_in[0];
    const int*   ei = (const int*)d_in[1];
    const float* l0w[8]; const float* l1w[8];
    for (int i = 0; i < 8; ++i) { l0w[i] = (const float*)d_in[2 + i]; l1w[i] = (const float*)d_in[10 + i]; }
    const float* Wout = (const float*)d_in[18];
    const float* bout = (const float*)d_in[19];
    float* out = (float*)d_out;

    // workspace layout
    float* ws = (float*)d_ws;
    float* qs   = ws;                           // NN*160 floats
    float* h0   = qs + (size_t)NN * QS_W;       // NN*32
    float* Wp0  = h0 + (size_t)NN * HID;        // 128*416
    float* bp0  = Wp0 + 128 * COLS;             // 416
    float* Wp1  = bp0 + COLS;                   // 32*416
    float* bp1  = Wp1 + 32 * COLS;              // 416
    unsigned short* kvb  = (unsigned short*)(bp1 + COLS);    // NN*256 bf16
    unsigned short* xh   = kvb + (size_t)NN * KV_W;          // NN*128
    unsigned short* xl   = xh + (size_t)NN * IN_DIM;         // NN*128
    unsigned short* hh   = xl + (size_t)NN * IN_DIM;         // NN*32
    unsigned short* hl   = hh + (size_t)NN * HID;            // NN*32
    unsigned short* Wf0h = hl + (size_t)NN * HID;            // 4*26*64*8
    unsigned short* Wf0l = Wf0h + 4 * NTILE * 64 * 8;
    unsigned short* Wf1h = Wf0l + 4 * NTILE * 64 * 8;        // 1*26*64*8
    unsigned short* Wf1l = Wf1h + NTILE * 64 * 8;
    int* ibase  = (int*)(Wf1l + NTILE * 64 * 8);
    int* deg     = ibase;                       // NN
    int* roff    = deg + NN;                    // NN+1
    int* woff    = roff + NN + 1;               // NN
    int* partial = woff + NN;                   // NB
    int* esrc    = partial + NB;                // EE

    // pack weights + fragment-pack + split-convert x
    pack_w<<<(128 * COLS + 255) / 256, 256, 0, stream>>>(
        l0w[0], l0w[1], l0w[2], l0w[3], l0w[4], l0w[5], l0w[6], l0w[7], Wp0, bp0, 128);
    pack_w<<<(32 * COLS + 255) / 256, 256, 0, stream>>>(
        l1w[0], l1w[1], l1w[2], l1w[3], l1w[4], l1w[5], l1w[6], l1w[7], Wp1, bp1, 32);
    pack_frag<<<(4 * NTILE * 64 + 255) / 256, 256, 0, stream>>>(Wp0, Wf0h, Wf0l, 128);
    pack_frag<<<(1 * NTILE * 64 + 255) / 256, 256, 0, stream>>>(Wp1, Wf1h, Wf1l, 32);
    to_bf16_split<<<(NN * IN_DIM / 4 + 255) / 256, 256, 0, stream>>>(x, xh, xl, NN * IN_DIM / 4);

    // CSR build (once; reused by both layers)
    zero_deg<<<(NN + 255) / 256, 256, 0, stream>>>(deg);
    hist_dst<<<(EE + 255) / 256, 256, 0, stream>>>(ei, deg);
    block_sum<<<NB, 256, 0, stream>>>(deg, partial);
    scan_partial<<<1, 64, 0, stream>>>(partial);
    block_scan<<<NB, 256, 0, stream>>>(deg, partial, roff, woff);
    scatter_edges<<<(EE + 255) / 256, 256, 0, stream>>>(ei, woff, esrc);

    const int RB = (NN + 127) / 128;             // 782
    const int gemm_blocks = 56 * ((RB + 7) / 8); // swizzle-bijective
    int attn_blocks = (NN * 64 + 255) / 256;     // one wave per node

    // layer 0
    gemm_mfma<<<gemm_blocks, 256, 0, stream>>>(xh, xl, Wf0h, Wf0l, bp0, qs, kvb, 128);
    fused_attn<<<attn_blocks, 256, 0, stream>>>(qs, kvb, roff, esrc, h0, hh, hl);

    // layer 1
    gemm_mfma<<<gemm_blocks, 256, 0, stream>>>(hh, hl, Wf1h, Wf1l, bp1, qs, kvb, 32);
    fused_attn<<<attn_blocks, 256, 0, stream>>>(qs, kvb, roff, esrc, h0, hh, hl);

    // output linear
    out_linear<<<(NN * OUT_DIM + 255) / 256, 256, 0, stream>>>(h0, Wout, bout, out);
}